// Round 1
// baseline (3021.385 us; speedup 1.0000x reference)
//
#include <hip/hip_runtime.h>
#include <stdint.h>

#define B_TOK 16384
#define D_MODEL 1024
#define H_EXP 4096
#define N_EXP 8

typedef unsigned int u32;
typedef unsigned short u16;
typedef __attribute__((ext_vector_type(8))) short short8;
typedef __attribute__((ext_vector_type(4))) float f32x4;

__device__ __forceinline__ u16 f2bf(float f) {
  u32 u = __float_as_uint(f);
  u32 r = (u + 0x7fffu + ((u >> 16) & 1u)) >> 16;
  return (u16)r;
}

__device__ __forceinline__ void gl_lds16(const void* g, void* l) {
  __builtin_amdgcn_global_load_lds(
      (const __attribute__((address_space(1))) u32*)g,
      (__attribute__((address_space(3))) u32*)l, 16, 0, 0);
}

// ---------------- gating GEMM1: h = relu(x @ gw1 + gb1), fp32 ----------------
// BM=128, BN=64, BK=16, 256 threads, each 8x4 outputs
__global__ __launch_bounds__(256) void k_gate_h(
    const float* __restrict__ x, const float* __restrict__ gw1,
    const float* __restrict__ gb1, float* __restrict__ hbuf)
{
  __shared__ float As[16][136];   // [k][m], padded
  __shared__ float Bs[16][64];    // [k][n]
  int m0 = blockIdx.x * 128, n0 = blockIdx.y * 64;
  int tid = threadIdx.x;
  int tx = tid & 15, ty = tid >> 4;
  float acc[8][4] = {};
  for (int kt = 0; kt < 1024; kt += 16) {
#pragma unroll
    for (int i = 0; i < 8; ++i) {
      int idx = tid + 256 * i;
      int r = idx >> 4, c = idx & 15;
      As[c][r] = x[(size_t)(m0 + r) * 1024 + kt + c];
    }
#pragma unroll
    for (int i = 0; i < 4; ++i) {
      int idx = tid + 256 * i;
      int r = idx >> 6, c = idx & 63;
      Bs[r][c] = gw1[(size_t)(kt + r) * 256 + n0 + c];
    }
    __syncthreads();
#pragma unroll
    for (int k = 0; k < 16; ++k) {
      float a[8], b[4];
#pragma unroll
      for (int mi = 0; mi < 8; ++mi) a[mi] = As[k][ty * 8 + mi];
#pragma unroll
      for (int ni = 0; ni < 4; ++ni) b[ni] = Bs[k][tx * 4 + ni];
#pragma unroll
      for (int mi = 0; mi < 8; ++mi)
#pragma unroll
        for (int ni = 0; ni < 4; ++ni)
          acc[mi][ni] += a[mi] * b[ni];
    }
    __syncthreads();
  }
#pragma unroll
  for (int mi = 0; mi < 8; ++mi) {
    int m = m0 + ty * 8 + mi;
#pragma unroll
    for (int ni = 0; ni < 4; ++ni) {
      int n = n0 + tx * 4 + ni;
      float v = acc[mi][ni] + gb1[n];
      hbuf[(size_t)m * 256 + n] = v > 0.f ? v : 0.f;
    }
  }
}

// ---------------- gating: logits, softmax, top-2, weights (one wave/token) ---
__global__ __launch_bounds__(256) void k_gate_top2(
    const float* __restrict__ hbuf, const float* __restrict__ gw2,
    const float* __restrict__ gb2, int* __restrict__ tok_idx,
    float* __restrict__ tok_w, int* __restrict__ counts,
    float* __restrict__ out_idx)
{
  int wave = threadIdx.x >> 6, lane = threadIdx.x & 63;
  int t = blockIdx.x * 4 + wave;
  float v[8] = {};
  const float* hr = hbuf + (size_t)t * 256;
#pragma unroll
  for (int i = 0; i < 4; ++i) {
    int j = lane + 64 * i;
    float h = hr[j];
#pragma unroll
    for (int e = 0; e < 8; ++e) v[e] += h * gw2[j * 8 + e];
  }
#pragma unroll
  for (int off = 32; off; off >>= 1) {
#pragma unroll
    for (int e = 0; e < 8; ++e) v[e] += __shfl_down(v[e], off);
  }
  if (lane == 0) {
    float l[8];
#pragma unroll
    for (int e = 0; e < 8; ++e) l[e] = v[e] + gb2[e];
    int i1 = 0; float b1 = l[0];
#pragma unroll
    for (int e = 1; e < 8; ++e) { if (l[e] > b1) { b1 = l[e]; i1 = e; } }
    int i2 = -1; float b2 = -3.4e38f;
#pragma unroll
    for (int e = 0; e < 8; ++e) { if (e == i1) continue; if (l[e] > b2) { b2 = l[e]; i2 = e; } }
    float w1 = 1.f / (1.f + expf(b2 - b1));   // = p1/(p1+p2)
    float w2 = 1.f - w1;
    tok_idx[t * 2] = i1; tok_idx[t * 2 + 1] = i2;
    tok_w[t * 2] = w1;  tok_w[t * 2 + 1] = w2;
    atomicAdd(&counts[i1], 1); atomicAdd(&counts[i2], 1);
    out_idx[t * 2] = (float)i1; out_idx[t * 2 + 1] = (float)i2;
  }
}

__global__ void k_offsets(const int* counts, int* offs, int* counts2) {
  if (threadIdx.x == 0) {
    int acc = 0;
    for (int e = 0; e < 8; ++e) { offs[e] = acc; acc += (counts[e] + 127) & ~127; }
    offs[8] = acc;
  }
  if (threadIdx.x < 8) counts2[threadIdx.x] = 0;
}

__global__ __launch_bounds__(256) void k_perm_init(int* perm, float* aw) {
  int i = blockIdx.x * 256 + threadIdx.x;
  if (i < 33792) { perm[i] = 0; aw[i] = 0.f; }   // pads: token 0 with weight 0
}

__global__ __launch_bounds__(256) void k_scatter(
    const int* tok_idx, const float* tok_w, const int* offs,
    int* counts2, int* perm, float* aw)
{
  int t = blockIdx.x * 256 + threadIdx.x;
#pragma unroll
  for (int j = 0; j < 2; ++j) {
    int e = tok_idx[t * 2 + j];
    int p = atomicAdd(&counts2[e], 1);
    int slot = offs[e] + p;
    perm[slot] = t;
    aw[slot] = tok_w[t * 2 + j];
  }
}

__global__ __launch_bounds__(256) void k_cast_x(const float* __restrict__ x,
                                                u16* __restrict__ xb) {
  int i = (blockIdx.x * 256 + threadIdx.x) * 4;
  const float4 v = *(const float4*)(x + i);
  ushort4 o;
  o.x = f2bf(v.x); o.y = f2bf(v.y); o.z = f2bf(v.z); o.w = f2bf(v.w);
  *(ushort4*)(xb + i) = o;
}

// in [M][N] fp32 -> out [N][M] bf16
__global__ __launch_bounds__(256) void k_transpose_bf16(
    const float* __restrict__ in, u16* __restrict__ out, int M, int N)
{
  __shared__ float tile[32][33];
  int n0 = blockIdx.x * 32, m0 = blockIdx.y * 32;
  int tx = threadIdx.x & 31, ty = threadIdx.x >> 5;  // 32x8
#pragma unroll
  for (int i = 0; i < 4; ++i)
    tile[ty + i * 8][tx] = in[(size_t)(m0 + ty + i * 8) * N + n0 + tx];
  __syncthreads();
#pragma unroll
  for (int i = 0; i < 4; ++i)
    out[(size_t)(n0 + ty + i * 8) * M + m0 + tx] = f2bf(tile[tx][ty + i * 8]);
}

// ------------- expert GEMM1: y1 = tanh(Xg @ w1 + b1) -> bf16 [rows][Hc] ------
// 128x128 tile, BK=32, 4 waves (2x2), m97-style global_load_lds staging
__global__ __launch_bounds__(256) void k_gemm1(
    const u16* __restrict__ xb, const u16* __restrict__ w1T,
    const float* __restrict__ eb1, const int* __restrict__ offs,
    const int* __restrict__ perm, u16* __restrict__ y1,
    int e, int h0, int Hc)
{
  int base = offs[e];
  int padded = offs[e + 1] - base;
  int m0 = blockIdx.x * 128;
  if (m0 >= padded) return;
  int hcol0 = blockIdx.y * 128;
  int hglob = h0 + hcol0;

  __shared__ u16 As[128 * 32];
  __shared__ u16 Bs[128 * 32];

  int tid = threadIdx.x, lane = tid & 63, wave = tid >> 6;
  int kq = lane & 3;
  const u16* aptr[2]; const u16* bptr[2]; u16* alds[2]; u16* blds[2];
#pragma unroll
  for (int it = 0; it < 2; ++it) {
    int chunk = wave * 2 + it;
    int r = chunk * 16 + (lane >> 2);
    int tok = perm[base + m0 + r];
    aptr[it] = xb + (size_t)tok * 1024 + kq * 8;
    bptr[it] = w1T + (size_t)(hglob + r) * 1024 + kq * 8;
    alds[it] = As + chunk * 512 + lane * 8;
    blds[it] = Bs + chunk * 512 + lane * 8;
  }

  f32x4 acc[4][4] = {};
  int wm = (wave & 1) * 64, wn = (wave >> 1) * 64;
  int frow = lane & 15, fq = lane >> 4;

  for (int kt = 0; kt < 1024; kt += 32) {
#pragma unroll
    for (int it = 0; it < 2; ++it) {
      gl_lds16(aptr[it] + kt, alds[it]);
      gl_lds16(bptr[it] + kt, blds[it]);
    }
    __syncthreads();
    short8 af[4], bf[4];
#pragma unroll
    for (int i = 0; i < 4; ++i)
      af[i] = *(const short8*)(As + (wm + i * 16 + frow) * 32 + fq * 8);
#pragma unroll
    for (int j = 0; j < 4; ++j)
      bf[j] = *(const short8*)(Bs + (wn + j * 16 + frow) * 32 + fq * 8);
#pragma unroll
    for (int i = 0; i < 4; ++i)
#pragma unroll
      for (int j = 0; j < 4; ++j)
        acc[i][j] = __builtin_amdgcn_mfma_f32_16x16x32_bf16(af[i], bf[j], acc[i][j], 0, 0, 0);
    __syncthreads();
  }

  int col = lane & 15, qr = (lane >> 4) * 4;
#pragma unroll
  for (int j = 0; j < 4; ++j) {
    int n = wn + j * 16 + col;
    float bias = eb1[e * 4096 + hglob + n];
#pragma unroll
    for (int i = 0; i < 4; ++i) {
#pragma unroll
      for (int r = 0; r < 4; ++r) {
        int m = wm + i * 16 + qr + r;
        float v = tanhf(acc[i][j][r] + bias);
        y1[(size_t)(m0 + m) * Hc + hcol0 + n] = f2bf(v);
      }
    }
  }
}

// ------------- expert GEMM2: out[tok] += w * (y1 @ w2 [+ b2 on chunk 0]) -----
__global__ __launch_bounds__(256) void k_gemm2(
    const u16* __restrict__ y1, const u16* __restrict__ w2T,
    const float* __restrict__ eb2, const int* __restrict__ offs,
    const int* __restrict__ perm, const float* __restrict__ aw,
    float* __restrict__ out, int e, int h0, int Hc)
{
  int base = offs[e];
  int padded = offs[e + 1] - base;
  int m0 = blockIdx.x * 128;
  if (m0 >= padded) return;
  int n0 = blockIdx.y * 128;

  __shared__ u16 As[128 * 32];
  __shared__ u16 Bs[128 * 32];

  int tid = threadIdx.x, lane = tid & 63, wave = tid >> 6;
  int kq = lane & 3;
  const u16* aptr[2]; const u16* bptr[2]; u16* alds[2]; u16* blds[2];
#pragma unroll
  for (int it = 0; it < 2; ++it) {
    int chunk = wave * 2 + it;
    int r = chunk * 16 + (lane >> 2);
    aptr[it] = y1 + (size_t)(m0 + r) * Hc + kq * 8;
    bptr[it] = w2T + (size_t)(n0 + r) * 4096 + h0 + kq * 8;
    alds[it] = As + chunk * 512 + lane * 8;
    blds[it] = Bs + chunk * 512 + lane * 8;
  }

  f32x4 acc[4][4] = {};
  int wm = (wave & 1) * 64, wn = (wave >> 1) * 64;
  int frow = lane & 15, fq = lane >> 4;

  for (int kt = 0; kt < Hc; kt += 32) {
#pragma unroll
    for (int it = 0; it < 2; ++it) {
      gl_lds16(aptr[it] + kt, alds[it]);
      gl_lds16(bptr[it] + kt, blds[it]);
    }
    __syncthreads();
    short8 af[4], bf[4];
#pragma unroll
    for (int i = 0; i < 4; ++i)
      af[i] = *(const short8*)(As + (wm + i * 16 + frow) * 32 + fq * 8);
#pragma unroll
    for (int j = 0; j < 4; ++j)
      bf[j] = *(const short8*)(Bs + (wn + j * 16 + frow) * 32 + fq * 8);
#pragma unroll
    for (int i = 0; i < 4; ++i)
#pragma unroll
      for (int j = 0; j < 4; ++j)
        acc[i][j] = __builtin_amdgcn_mfma_f32_16x16x32_bf16(af[i], bf[j], acc[i][j], 0, 0, 0);
    __syncthreads();
  }

  int col = lane & 15, qr = (lane >> 4) * 4;
#pragma unroll
  for (int i = 0; i < 4; ++i) {
    int tokv[4]; float wv[4];
#pragma unroll
    for (int r = 0; r < 4; ++r) {
      int m = wm + i * 16 + qr + r;
      int slot = base + m0 + m;
      tokv[r] = perm[slot];
      wv[r] = aw[slot];       // pads have weight 0 -> atomicAdd(0) is a no-op
    }
#pragma unroll
    for (int j = 0; j < 4; ++j) {
      int n = wn + j * 16 + col;
      int d = n0 + n;
      float bias = (h0 == 0) ? eb2[e * 1024 + d] : 0.f;
#pragma unroll
      for (int r = 0; r < 4; ++r) {
        float v = acc[i][j][r] + bias;
        atomicAdd(out + (size_t)tokv[r] * 1024 + d, wv[r] * v);
      }
    }
  }
}

extern "C" void kernel_launch(void* const* d_in, const int* in_sizes, int n_in,
                              void* d_out, int out_size, void* d_ws, size_t ws_size,
                              hipStream_t stream)
{
  const float* x   = (const float*)d_in[0];
  const float* gw1 = (const float*)d_in[1];
  const float* gb1 = (const float*)d_in[2];
  const float* gw2 = (const float*)d_in[3];
  const float* gb2 = (const float*)d_in[4];
  const float* ew1 = (const float*)d_in[5];
  const float* eb1 = (const float*)d_in[6];
  const float* ew2 = (const float*)d_in[7];
  const float* eb2 = (const float*)d_in[8];
  float* out = (float*)d_out;

  char* ws = (char*)d_ws;
  int*   counts  = (int*)(ws + 0);
  int*   counts2 = (int*)(ws + 32);
  int*   offs    = (int*)(ws + 64);
  int*   tok_idx = (int*)(ws + 256);
  float* tok_w   = (float*)(ws + 131328);
  int*   perm    = (int*)(ws + 262400);
  float* aw      = (float*)(ws + 397568);
  u16*   xb      = (u16*)(ws + 1048576);
  u16*   w1T     = (u16*)(ws + 34603008);
  u16*   w2T     = (u16*)(ws + 42991616);
  char*  ybase   = ws + 51380224;
  float* hbuf    = (float*)ybase;   // 16 MB, dead before y1 is written
  u16*   y1      = (u16*)ybase;

  // H-chunk adapts to workspace: 4096 needs ~177 MB total, 512 needs ~65 MB
  int Hc = 512;
  for (int c = 4096; c >= 512; c >>= 1) {
    if (51380224ull + (size_t)16384 * c * 2 <= ws_size) { Hc = c; break; }
  }

  hipMemsetAsync(d_out, 0, (size_t)B_TOK * D_MODEL * 4, stream);
  hipMemsetAsync(d_ws, 0, 128, stream);

  k_gate_h<<<dim3(128, 4), 256, 0, stream>>>(x, gw1, gb1, hbuf);
  k_gate_top2<<<4096, 256, 0, stream>>>(hbuf, gw2, gb2, tok_idx, tok_w, counts,
                                        out + (size_t)B_TOK * D_MODEL);
  k_offsets<<<1, 64, 0, stream>>>(counts, offs, counts2);
  k_perm_init<<<132, 256, 0, stream>>>(perm, aw);
  k_scatter<<<64, 256, 0, stream>>>(tok_idx, tok_w, offs, counts2, perm, aw);
  k_cast_x<<<16384, 256, 0, stream>>>(x, xb);

  for (int e = 0; e < 8; ++e) {
    k_transpose_bf16<<<dim3(128, 32), 256, 0, stream>>>(
        ew1 + (size_t)e * 1024 * 4096, w1T, 1024, 4096);
    k_transpose_bf16<<<dim3(32, 128), 256, 0, stream>>>(
        ew2 + (size_t)e * 4096 * 1024, w2T, 4096, 1024);
    for (int h0 = 0; h0 < 4096; h0 += Hc) {
      k_gemm1<<<dim3(128, Hc / 128), 256, 0, stream>>>(xb, w1T, eb1, offs, perm, y1, e, h0, Hc);
      k_gemm2<<<dim3(128, 8), 256, 0, stream>>>(y1, w2T, eb2, offs, perm, aw, out, e, h0, Hc);
    }
  }
}

// Round 2
// 1681.923 us; speedup vs baseline: 1.7964x; 1.7964x over previous
//
#include <hip/hip_runtime.h>
#include <stdint.h>

#define B_TOK 16384
#define D_MODEL 1024
#define H_EXP 4096
#define N_EXP 8
#define SLOT_MAX 33792   // 32768 + 8*127 rounded up to 128

typedef unsigned int u32;
typedef unsigned short u16;
typedef __attribute__((ext_vector_type(8))) short short8;
typedef __attribute__((ext_vector_type(4))) float f32x4;

__device__ __forceinline__ u16 f2bf(float f) {
  u32 u = __float_as_uint(f);
  u32 r = (u + 0x7fffu + ((u >> 16) & 1u)) >> 16;
  return (u16)r;
}

__device__ __forceinline__ void gl_lds16(const void* g, void* l) {
  __builtin_amdgcn_global_load_lds(
      (const __attribute__((address_space(1))) u32*)g,
      (__attribute__((address_space(3))) u32*)l, 16, 0, 0);
}

// ---------------- gating GEMM1: h = relu(x @ gw1 + gb1), fp32 ----------------
// BM=128, BN=128, BK=16, 256 threads as 16x16, each 8x8 outputs
__global__ __launch_bounds__(256) void k_gate_h(
    const float* __restrict__ x, const float* __restrict__ gw1,
    const float* __restrict__ gb1, float* __restrict__ hbuf)
{
  __shared__ float As[16][132];   // [k][m]; 132*4=528 bytes/row, 16B-divisible
  __shared__ float Bs[16][128];   // [k][n]
  int m0 = blockIdx.x * 128, n0 = blockIdx.y * 128;
  int tid = threadIdx.x;
  int tx = tid & 15, ty = tid >> 4;
  float acc[8][8] = {};
  for (int kt = 0; kt < 1024; kt += 16) {
#pragma unroll
    for (int i = 0; i < 8; ++i) {
      int idx = tid + 256 * i;
      int r = idx >> 4, c = idx & 15;
      As[c][r] = x[(size_t)(m0 + r) * 1024 + kt + c];
    }
#pragma unroll
    for (int i = 0; i < 8; ++i) {
      int idx = tid + 256 * i;
      int r = idx >> 7, c = idx & 127;
      Bs[r][c] = gw1[(size_t)(kt + r) * 256 + n0 + c];
    }
    __syncthreads();
#pragma unroll
    for (int k = 0; k < 16; ++k) {
      float a[8], b[8];
#pragma unroll
      for (int mi = 0; mi < 8; ++mi) a[mi] = As[k][ty * 8 + mi];
#pragma unroll
      for (int ni = 0; ni < 8; ++ni) b[ni] = Bs[k][tx * 8 + ni];
#pragma unroll
      for (int mi = 0; mi < 8; ++mi)
#pragma unroll
        for (int ni = 0; ni < 8; ++ni)
          acc[mi][ni] += a[mi] * b[ni];
    }
    __syncthreads();
  }
#pragma unroll
  for (int mi = 0; mi < 8; ++mi) {
    int m = m0 + ty * 8 + mi;
#pragma unroll
    for (int ni = 0; ni < 8; ++ni) {
      int n = n0 + tx * 8 + ni;
      float v = acc[mi][ni] + gb1[n];
      hbuf[(size_t)m * 256 + n] = v > 0.f ? v : 0.f;
    }
  }
}

// ---------------- gating: logits, top-2, weights (one wave/token, NO atomics)
__global__ __launch_bounds__(256) void k_gate_top2(
    const float* __restrict__ hbuf, const float* __restrict__ gw2,
    const float* __restrict__ gb2, int* __restrict__ tok_idx,
    float* __restrict__ tok_w, float* __restrict__ out_idx)
{
  int wave = threadIdx.x >> 6, lane = threadIdx.x & 63;
  int t = blockIdx.x * 4 + wave;
  float v[8] = {};
  const float* hr = hbuf + (size_t)t * 256;
#pragma unroll
  for (int i = 0; i < 4; ++i) {
    int j = lane + 64 * i;
    float h = hr[j];
#pragma unroll
    for (int e = 0; e < 8; ++e) v[e] += h * gw2[j * 8 + e];
  }
#pragma unroll
  for (int off = 32; off; off >>= 1) {
#pragma unroll
    for (int e = 0; e < 8; ++e) v[e] += __shfl_down(v[e], off);
  }
  if (lane == 0) {
    float l[8];
#pragma unroll
    for (int e = 0; e < 8; ++e) l[e] = v[e] + gb2[e];
    int i1 = 0; float b1 = l[0];
#pragma unroll
    for (int e = 1; e < 8; ++e) { if (l[e] > b1) { b1 = l[e]; i1 = e; } }
    int i2 = -1; float b2 = -3.4e38f;
#pragma unroll
    for (int e = 0; e < 8; ++e) { if (e == i1) continue; if (l[e] > b2) { b2 = l[e]; i2 = e; } }
    float w1 = 1.f / (1.f + expf(b2 - b1));   // = p1/(p1+p2)
    float w2 = 1.f - w1;
    tok_idx[t * 2] = i1; tok_idx[t * 2 + 1] = i2;
    tok_w[t * 2] = w1;  tok_w[t * 2 + 1] = w2;
    out_idx[t * 2] = (float)i1; out_idx[t * 2 + 1] = (float)i2;
  }
}

// ---------------- histogram of expert assignments (LDS-aggregated) ----------
__global__ __launch_bounds__(256) void k_count(const int* __restrict__ tok_idx,
                                               int* __restrict__ counts)
{
  __shared__ int h[8];
  if (threadIdx.x < 8) h[threadIdx.x] = 0;
  __syncthreads();
  int4 v = ((const int4*)tok_idx)[blockIdx.x * 256 + threadIdx.x];
  atomicAdd(&h[v.x], 1); atomicAdd(&h[v.y], 1);
  atomicAdd(&h[v.z], 1); atomicAdd(&h[v.w], 1);
  __syncthreads();
  if (threadIdx.x < 8) atomicAdd(&counts[threadIdx.x], h[threadIdx.x]);
}

__global__ void k_offsets(const int* counts, int* offs) {
  if (threadIdx.x == 0) {
    int acc = 0;
    for (int e = 0; e < 8; ++e) { offs[e] = acc; acc += (counts[e] + 127) & ~127; }
    offs[8] = acc;
  }
}

__global__ __launch_bounds__(256) void k_perm_init(int* perm, float* aw) {
  int i = blockIdx.x * 256 + threadIdx.x;
  if (i < SLOT_MAX) { perm[i] = 0; aw[i] = 0.f; }  // pads: token 0 with weight 0
}

// ---------------- scatter (LDS-aggregated reservation, 512 global atomics) --
__global__ __launch_bounds__(256) void k_scatter(
    const int* __restrict__ tok_idx, const float* __restrict__ tok_w,
    const int* __restrict__ offs, int* __restrict__ counts2,
    int* __restrict__ perm, float* __restrict__ aw)
{
  __shared__ int lcnt[8], lbase[8];
  int tid = threadIdx.x;
  if (tid < 8) lcnt[tid] = 0;
  __syncthreads();
  int t = blockIdx.x * 256 + tid;
  int e0 = tok_idx[t * 2], e1 = tok_idx[t * 2 + 1];
  int r0 = atomicAdd(&lcnt[e0], 1);
  int r1 = atomicAdd(&lcnt[e1], 1);
  __syncthreads();
  if (tid < 8) lbase[tid] = atomicAdd(&counts2[tid], lcnt[tid]);
  __syncthreads();
  int s0 = offs[e0] + lbase[e0] + r0;
  int s1 = offs[e1] + lbase[e1] + r1;
  perm[s0] = t; aw[s0] = tok_w[t * 2];
  perm[s1] = t; aw[s1] = tok_w[t * 2 + 1];
}

__global__ __launch_bounds__(256) void k_cast_x(const float* __restrict__ x,
                                                u16* __restrict__ xb) {
  int i = (blockIdx.x * 256 + threadIdx.x) * 4;
  const float4 v = *(const float4*)(x + i);
  ushort4 o;
  o.x = f2bf(v.x); o.y = f2bf(v.y); o.z = f2bf(v.z); o.w = f2bf(v.w);
  *(ushort4*)(xb + i) = o;
}

// ---- transpose slice -> bf16, per expert (blockIdx.z) ----
// out[n*out_stride + m] = in[(row_off+m)*in_stride + col_off+n]
__global__ __launch_bounds__(256) void k_trans(
    const float* __restrict__ in, u16* __restrict__ out,
    int in_stride, int row_off, int col_off, int out_stride,
    int in_esz, int out_esz)
{
  __shared__ float tile[32][33];
  int e = blockIdx.z;
  in += (size_t)e * in_esz;
  out += (size_t)e * out_esz;
  int n0 = blockIdx.x * 32, m0 = blockIdx.y * 32;
  int tx = threadIdx.x & 31, ty = threadIdx.x >> 5;  // 32x8
#pragma unroll
  for (int i = 0; i < 4; ++i)
    tile[ty + i * 8][tx] =
        in[(size_t)(row_off + m0 + ty + i * 8) * in_stride + col_off + n0 + tx];
  __syncthreads();
#pragma unroll
  for (int i = 0; i < 4; ++i)
    out[(size_t)(n0 + ty + i * 8) * out_stride + m0 + tx] = f2bf(tile[tx][ty + i * 8]);
}

__device__ __forceinline__ int find_expert(const int* offs, int m0) {
  int e = 0;
#pragma unroll
  for (int i = 1; i < 8; ++i) e += (m0 >= offs[i]);
  return e;
}

// ------------- expert GEMM1 (all experts batched): y1 = tanh(Xg@w1+b1) bf16 -
// 128x128 tile, BK=32, 4 waves (2x2), global slot rows
__global__ __launch_bounds__(256) void k_gemm1(
    const u16* __restrict__ xb, const u16* __restrict__ wTc,
    const float* __restrict__ eb1, const int* __restrict__ offs,
    const int* __restrict__ perm, u16* __restrict__ y1,
    int h0, int Hc)
{
  int m0 = blockIdx.x * 128;
  if (m0 >= offs[8]) return;
  int e = find_expert(offs, m0);
  int hcol0 = blockIdx.y * 128;

  __shared__ u16 As[128 * 32];
  __shared__ u16 Bs[128 * 32];

  int tid = threadIdx.x, lane = tid & 63, wave = tid >> 6;
  int kq = lane & 3;
  const u16* wbase = wTc + (size_t)e * Hc * 1024;
  const u16* aptr[2]; const u16* bptr[2]; u16* alds[2]; u16* blds[2];
#pragma unroll
  for (int it = 0; it < 2; ++it) {
    int chunk = wave * 2 + it;
    int r = chunk * 16 + (lane >> 2);
    int tok = perm[m0 + r];
    aptr[it] = xb + (size_t)tok * 1024 + kq * 8;
    bptr[it] = wbase + (size_t)(hcol0 + r) * 1024 + kq * 8;
    alds[it] = As + chunk * 512 + lane * 8;
    blds[it] = Bs + chunk * 512 + lane * 8;
  }

  f32x4 acc[4][4] = {};
  int wm = (wave & 1) * 64, wn = (wave >> 1) * 64;
  int frow = lane & 15, fq = lane >> 4;

  for (int kt = 0; kt < 1024; kt += 32) {
#pragma unroll
    for (int it = 0; it < 2; ++it) {
      gl_lds16(aptr[it] + kt, alds[it]);
      gl_lds16(bptr[it] + kt, blds[it]);
    }
    __syncthreads();
    short8 af[4], bf[4];
#pragma unroll
    for (int i = 0; i < 4; ++i)
      af[i] = *(const short8*)(As + (wm + i * 16 + frow) * 32 + fq * 8);
#pragma unroll
    for (int j = 0; j < 4; ++j)
      bf[j] = *(const short8*)(Bs + (wn + j * 16 + frow) * 32 + fq * 8);
#pragma unroll
    for (int i = 0; i < 4; ++i)
#pragma unroll
      for (int j = 0; j < 4; ++j)
        acc[i][j] = __builtin_amdgcn_mfma_f32_16x16x32_bf16(af[i], bf[j], acc[i][j], 0, 0, 0);
    __syncthreads();
  }

  int col = lane & 15, qr = (lane >> 4) * 4;
#pragma unroll
  for (int j = 0; j < 4; ++j) {
    int n = wn + j * 16 + col;
    float bias = eb1[e * 4096 + h0 + hcol0 + n];
#pragma unroll
    for (int i = 0; i < 4; ++i) {
#pragma unroll
      for (int r = 0; r < 4; ++r) {
        int m = wm + i * 16 + qr + r;
        float v = tanhf(acc[i][j][r] + bias);
        y1[(size_t)(m0 + m) * Hc + hcol0 + n] = f2bf(v);
      }
    }
  }
}

// ------------- expert GEMM2 (batched): out[tok] += w * (y1 @ w2 [+ b2]) -----
__global__ __launch_bounds__(256) void k_gemm2(
    const u16* __restrict__ y1, const u16* __restrict__ wTc,
    const float* __restrict__ eb2, const int* __restrict__ offs,
    const int* __restrict__ perm, const float* __restrict__ aw,
    float* __restrict__ out, int h0, int Hc)
{
  int m0 = blockIdx.x * 128;
  if (m0 >= offs[8]) return;
  int e = find_expert(offs, m0);
  int n0 = blockIdx.y * 128;

  __shared__ u16 As[128 * 32];
  __shared__ u16 Bs[128 * 32];

  int tid = threadIdx.x, lane = tid & 63, wave = tid >> 6;
  int kq = lane & 3;
  const u16* wbase = wTc + (size_t)e * 1024 * Hc;
  const u16* aptr[2]; const u16* bptr[2]; u16* alds[2]; u16* blds[2];
#pragma unroll
  for (int it = 0; it < 2; ++it) {
    int chunk = wave * 2 + it;
    int r = chunk * 16 + (lane >> 2);
    aptr[it] = y1 + (size_t)(m0 + r) * Hc + kq * 8;
    bptr[it] = wbase + (size_t)(n0 + r) * Hc + kq * 8;
    alds[it] = As + chunk * 512 + lane * 8;
    blds[it] = Bs + chunk * 512 + lane * 8;
  }

  f32x4 acc[4][4] = {};
  int wm = (wave & 1) * 64, wn = (wave >> 1) * 64;
  int frow = lane & 15, fq = lane >> 4;

  for (int kt = 0; kt < Hc; kt += 32) {
#pragma unroll
    for (int it = 0; it < 2; ++it) {
      gl_lds16(aptr[it] + kt, alds[it]);
      gl_lds16(bptr[it] + kt, blds[it]);
    }
    __syncthreads();
    short8 af[4], bf[4];
#pragma unroll
    for (int i = 0; i < 4; ++i)
      af[i] = *(const short8*)(As + (wm + i * 16 + frow) * 32 + fq * 8);
#pragma unroll
    for (int j = 0; j < 4; ++j)
      bf[j] = *(const short8*)(Bs + (wn + j * 16 + frow) * 32 + fq * 8);
#pragma unroll
    for (int i = 0; i < 4; ++i)
#pragma unroll
      for (int j = 0; j < 4; ++j)
        acc[i][j] = __builtin_amdgcn_mfma_f32_16x16x32_bf16(af[i], bf[j], acc[i][j], 0, 0, 0);
    __syncthreads();
  }

  int col = lane & 15, qr = (lane >> 4) * 4;
#pragma unroll
  for (int i = 0; i < 4; ++i) {
    int tokv[4]; float wv[4];
#pragma unroll
    for (int r = 0; r < 4; ++r) {
      int slot = m0 + wm + i * 16 + qr + r;
      tokv[r] = perm[slot];
      wv[r] = aw[slot];       // pads have weight 0 -> atomicAdd(0) is a no-op
    }
#pragma unroll
    for (int j = 0; j < 4; ++j) {
      int d = n0 + wn + j * 16 + col;
      float bias = (h0 == 0) ? eb2[e * 1024 + d] : 0.f;
#pragma unroll
      for (int r = 0; r < 4; ++r) {
        float v = acc[i][j][r] + bias;
        atomicAdd(out + (size_t)tokv[r] * 1024 + d, wv[r] * v);
      }
    }
  }
}

extern "C" void kernel_launch(void* const* d_in, const int* in_sizes, int n_in,
                              void* d_out, int out_size, void* d_ws, size_t ws_size,
                              hipStream_t stream)
{
  const float* x   = (const float*)d_in[0];
  const float* gw1 = (const float*)d_in[1];
  const float* gb1 = (const float*)d_in[2];
  const float* gw2 = (const float*)d_in[3];
  const float* gb2 = (const float*)d_in[4];
  const float* ew1 = (const float*)d_in[5];
  const float* eb1 = (const float*)d_in[6];
  const float* ew2 = (const float*)d_in[7];
  const float* eb2 = (const float*)d_in[8];
  float* out = (float*)d_out;

  char* ws = (char*)d_ws;
  int*   counts  = (int*)(ws + 0);
  int*   counts2 = (int*)(ws + 32);
  int*   offs    = (int*)(ws + 64);
  int*   tok_idx = (int*)(ws + 256);
  float* tok_w   = (float*)(ws + 131328);
  int*   perm    = (int*)(ws + 262400);
  float* aw      = (float*)(ws + 397568);
  u16*   xb      = (u16*)(ws + 1048576);           // 33.55 MB
  char*  wbase   = ws + 34603008;

  // Hc ladder: need = 34603008 + (16384 /*wTc*/ + 67584 /*y1*/) * Hc
  int Hc = 256;
  for (int c = 4096; c >= 256; c >>= 1) {
    if (34603008ull + 83968ull * c <= ws_size) { Hc = c; break; }
  }
  u16*   wTc  = (u16*)wbase;                        // shared w1T/w2T chunk buf
  u16*   y1   = (u16*)(wbase + (size_t)16384 * Hc); // SLOT_MAX x Hc bf16
  float* hbuf = (float*)y1;                         // 16 MB alias, dead pre-gemm

  hipMemsetAsync(d_out, 0, (size_t)B_TOK * D_MODEL * 4, stream);
  hipMemsetAsync(d_ws, 0, 64, stream);   // counts + counts2

  k_gate_h<<<dim3(128, 2), 256, 0, stream>>>(x, gw1, gb1, hbuf);
  k_gate_top2<<<4096, 256, 0, stream>>>(hbuf, gw2, gb2, tok_idx, tok_w,
                                        out + (size_t)B_TOK * D_MODEL);
  k_count<<<32, 256, 0, stream>>>(tok_idx, counts);
  k_offsets<<<1, 64, 0, stream>>>(counts, offs);
  k_perm_init<<<132, 256, 0, stream>>>(perm, aw);
  k_scatter<<<64, 256, 0, stream>>>(tok_idx, tok_w, offs, counts2, perm, aw);
  k_cast_x<<<16384, 256, 0, stream>>>(x, xb);

  for (int h0 = 0; h0 < 4096; h0 += Hc) {
    // w1 slice: out[n*1024+m] = ew1[e][m*4096 + h0+n], n in [0,Hc), m in [0,1024)
    k_trans<<<dim3(Hc / 32, 32, 8), 256, 0, stream>>>(
        ew1, wTc, 4096, 0, h0, 1024, 1024 * 4096, Hc * 1024);
    k_gemm1<<<dim3(SLOT_MAX / 128, Hc / 128), 256, 0, stream>>>(
        xb, wTc, eb1, offs, perm, y1, h0, Hc);
    // w2 slice: out[d*Hc+m] = ew2[e][(h0+m)*1024 + d], d in [0,1024), m in [0,Hc)
    k_trans<<<dim3(32, Hc / 32, 8), 256, 0, stream>>>(
        ew2, wTc, 1024, h0, 0, Hc, 4096 * 1024, 1024 * Hc);
    k_gemm2<<<dim3(SLOT_MAX / 128, 8), 256, 0, stream>>>(
        y1, wTc, eb2, offs, perm, aw, out, h0, Hc);
  }
}

// Round 3
// 1428.469 us; speedup vs baseline: 2.1151x; 1.1774x over previous
//
#include <hip/hip_runtime.h>
#include <stdint.h>

#define B_TOK 16384
#define D_MODEL 1024
#define H_EXP 4096
#define N_EXP 8
#define SLOT_MAX 33792   // 32768 + 8*127 rounded up to 128

typedef unsigned int u32;
typedef unsigned short u16;
typedef __attribute__((ext_vector_type(8))) short short8;
typedef __attribute__((ext_vector_type(4))) float f32x4;

__device__ __forceinline__ u16 f2bf(float f) {
  u32 u = __float_as_uint(f);
  u32 r = (u + 0x7fffu + ((u >> 16) & 1u)) >> 16;
  return (u16)r;
}

__device__ __forceinline__ float fast_tanh(float x) {
  x = fminf(15.f, fmaxf(-15.f, x));
  float t = __expf(2.f * x);          // v_exp_f32 path
  return (t - 1.f) / (t + 1.f);
}

__device__ __forceinline__ void gl_lds16(const void* g, void* l) {
  __builtin_amdgcn_global_load_lds(
      (const __attribute__((address_space(1))) u32*)g,
      (__attribute__((address_space(3))) u32*)l, 16, 0, 0);
}

// ---------------- gating GEMM1: h = relu(x @ gw1 + gb1), fp32 ----------------
__global__ __launch_bounds__(256) void k_gate_h(
    const float* __restrict__ x, const float* __restrict__ gw1,
    const float* __restrict__ gb1, float* __restrict__ hbuf)
{
  __shared__ float As[16][132];
  __shared__ float Bs[16][128];
  int m0 = blockIdx.x * 128, n0 = blockIdx.y * 128;
  int tid = threadIdx.x;
  int tx = tid & 15, ty = tid >> 4;
  float acc[8][8] = {};
  for (int kt = 0; kt < 1024; kt += 16) {
#pragma unroll
    for (int i = 0; i < 8; ++i) {
      int idx = tid + 256 * i;
      int r = idx >> 4, c = idx & 15;
      As[c][r] = x[(size_t)(m0 + r) * 1024 + kt + c];
    }
#pragma unroll
    for (int i = 0; i < 8; ++i) {
      int idx = tid + 256 * i;
      int r = idx >> 7, c = idx & 127;
      Bs[r][c] = gw1[(size_t)(kt + r) * 256 + n0 + c];
    }
    __syncthreads();
#pragma unroll
    for (int k = 0; k < 16; ++k) {
      float a[8], b[8];
#pragma unroll
      for (int mi = 0; mi < 8; ++mi) a[mi] = As[k][ty * 8 + mi];
#pragma unroll
      for (int ni = 0; ni < 8; ++ni) b[ni] = Bs[k][tx * 8 + ni];
#pragma unroll
      for (int mi = 0; mi < 8; ++mi)
#pragma unroll
        for (int ni = 0; ni < 8; ++ni)
          acc[mi][ni] += a[mi] * b[ni];
    }
    __syncthreads();
  }
#pragma unroll
  for (int mi = 0; mi < 8; ++mi) {
    int m = m0 + ty * 8 + mi;
#pragma unroll
    for (int ni = 0; ni < 8; ++ni) {
      int n = n0 + tx * 8 + ni;
      float v = acc[mi][ni] + gb1[n];
      hbuf[(size_t)m * 256 + n] = v > 0.f ? v : 0.f;
    }
  }
}

// ---------------- gating: logits, top-2, weights (one wave/token) -----------
__global__ __launch_bounds__(256) void k_gate_top2(
    const float* __restrict__ hbuf, const float* __restrict__ gw2,
    const float* __restrict__ gb2, int* __restrict__ tok_idx,
    float* __restrict__ tok_w, float* __restrict__ out_idx)
{
  int wave = threadIdx.x >> 6, lane = threadIdx.x & 63;
  int t = blockIdx.x * 4 + wave;
  float v[8] = {};
  const float* hr = hbuf + (size_t)t * 256;
#pragma unroll
  for (int i = 0; i < 4; ++i) {
    int j = lane + 64 * i;
    float h = hr[j];
#pragma unroll
    for (int e = 0; e < 8; ++e) v[e] += h * gw2[j * 8 + e];
  }
#pragma unroll
  for (int off = 32; off; off >>= 1) {
#pragma unroll
    for (int e = 0; e < 8; ++e) v[e] += __shfl_down(v[e], off);
  }
  if (lane == 0) {
    float l[8];
#pragma unroll
    for (int e = 0; e < 8; ++e) l[e] = v[e] + gb2[e];
    int i1 = 0; float b1 = l[0];
#pragma unroll
    for (int e = 1; e < 8; ++e) { if (l[e] > b1) { b1 = l[e]; i1 = e; } }
    int i2 = -1; float b2 = -3.4e38f;
#pragma unroll
    for (int e = 0; e < 8; ++e) { if (e == i1) continue; if (l[e] > b2) { b2 = l[e]; i2 = e; } }
    float w1 = 1.f / (1.f + expf(b2 - b1));
    float w2 = 1.f - w1;
    tok_idx[t * 2] = i1; tok_idx[t * 2 + 1] = i2;
    tok_w[t * 2] = w1;  tok_w[t * 2 + 1] = w2;
    out_idx[t * 2] = (float)i1; out_idx[t * 2 + 1] = (float)i2;
  }
}

__global__ __launch_bounds__(256) void k_count(const int* __restrict__ tok_idx,
                                               int* __restrict__ counts)
{
  __shared__ int h[8];
  if (threadIdx.x < 8) h[threadIdx.x] = 0;
  __syncthreads();
  int4 v = ((const int4*)tok_idx)[blockIdx.x * 256 + threadIdx.x];
  atomicAdd(&h[v.x], 1); atomicAdd(&h[v.y], 1);
  atomicAdd(&h[v.z], 1); atomicAdd(&h[v.w], 1);
  __syncthreads();
  if (threadIdx.x < 8) atomicAdd(&counts[threadIdx.x], h[threadIdx.x]);
}

__global__ void k_offsets(const int* counts, int* offs) {
  if (threadIdx.x == 0) {
    int acc = 0;
    for (int e = 0; e < 8; ++e) { offs[e] = acc; acc += (counts[e] + 127) & ~127; }
    offs[8] = acc;
  }
}

__global__ __launch_bounds__(256) void k_perm_init(int* perm, float* aw) {
  int i = blockIdx.x * 256 + threadIdx.x;
  if (i < SLOT_MAX) { perm[i] = 0; aw[i] = 0.f; }
}

__global__ __launch_bounds__(256) void k_scatter(
    const int* __restrict__ tok_idx, const float* __restrict__ tok_w,
    const int* __restrict__ offs, int* __restrict__ counts2,
    int* __restrict__ perm, float* __restrict__ aw)
{
  __shared__ int lcnt[8], lbase[8];
  int tid = threadIdx.x;
  if (tid < 8) lcnt[tid] = 0;
  __syncthreads();
  int t = blockIdx.x * 256 + tid;
  int e0 = tok_idx[t * 2], e1 = tok_idx[t * 2 + 1];
  int r0 = atomicAdd(&lcnt[e0], 1);
  int r1 = atomicAdd(&lcnt[e1], 1);
  __syncthreads();
  if (tid < 8) lbase[tid] = atomicAdd(&counts2[tid], lcnt[tid]);
  __syncthreads();
  int s0 = offs[e0] + lbase[e0] + r0;
  int s1 = offs[e1] + lbase[e1] + r1;
  perm[s0] = t; aw[s0] = tok_w[t * 2];
  perm[s1] = t; aw[s1] = tok_w[t * 2 + 1];
}

__global__ __launch_bounds__(256) void k_cast_x(const float* __restrict__ x,
                                                u16* __restrict__ xb) {
  int i = (blockIdx.x * 256 + threadIdx.x) * 4;
  const float4 v = *(const float4*)(x + i);
  ushort4 o;
  o.x = f2bf(v.x); o.y = f2bf(v.y); o.z = f2bf(v.z); o.w = f2bf(v.w);
  *(ushort4*)(xb + i) = o;
}

// ---- transpose slice -> bf16, per expert (blockIdx.z) ----
__global__ __launch_bounds__(256) void k_trans(
    const float* __restrict__ in, u16* __restrict__ out,
    int in_stride, int row_off, int col_off, int out_stride,
    int in_esz, int out_esz)
{
  __shared__ float tile[32][33];
  int e = blockIdx.z;
  in += (size_t)e * in_esz;
  out += (size_t)e * out_esz;
  int n0 = blockIdx.x * 32, m0 = blockIdx.y * 32;
  int tx = threadIdx.x & 31, ty = threadIdx.x >> 5;
#pragma unroll
  for (int i = 0; i < 4; ++i)
    tile[ty + i * 8][tx] =
        in[(size_t)(row_off + m0 + ty + i * 8) * in_stride + col_off + n0 + tx];
  __syncthreads();
#pragma unroll
  for (int i = 0; i < 4; ++i)
    out[(size_t)(n0 + ty + i * 8) * out_stride + m0 + tx] = f2bf(tile[tx][ty + i * 8]);
}

__device__ __forceinline__ int find_expert(const int* offs, int m0) {
  int e = 0;
#pragma unroll
  for (int i = 1; i < 8; ++i) e += (m0 >= offs[i]);
  return e;
}

// ------------- expert GEMM1 (batched): y1 = tanh(Xg@w1+b1) bf16 -------------
// grid: x = h-col tile (fastest, L2/L3 A-reuse), y = m tile
// LDS XOR swizzle: physical k-chunk = kq ^ ((row>>1)&3)  -> 2-way (free) reads
__global__ __launch_bounds__(256) void k_gemm1(
    const u16* __restrict__ xb, const u16* __restrict__ wTc,
    const float* __restrict__ eb1, const int* __restrict__ offs,
    const int* __restrict__ perm, u16* __restrict__ y1,
    int h0, int Hc)
{
  int m0 = blockIdx.y * 128;
  if (m0 >= offs[8]) return;
  int e = find_expert(offs, m0);
  int hcol0 = blockIdx.x * 128;

  __shared__ u16 As[128 * 32];
  __shared__ u16 Bs[128 * 32];

  int tid = threadIdx.x, lane = tid & 63, wave = tid >> 6;
  int kq = lane & 3;
  int ks = kq ^ ((lane >> 3) & 3);          // swizzled k-chunk this lane stages
  const u16* wbase = wTc + (size_t)e * Hc * 1024;
  const u16* aptr[2]; const u16* bptr[2]; u16* alds[2]; u16* blds[2];
#pragma unroll
  for (int it = 0; it < 2; ++it) {
    int chunk = wave * 2 + it;
    int r = chunk * 16 + (lane >> 2);
    int tok = perm[m0 + r];
    aptr[it] = xb + (size_t)tok * 1024 + ks * 8;
    bptr[it] = wbase + (size_t)(hcol0 + r) * 1024 + ks * 8;
    alds[it] = As + chunk * 512 + lane * 8;
    blds[it] = Bs + chunk * 512 + lane * 8;
  }

  f32x4 acc[4][4] = {};
  int wm = (wave & 1) * 64, wn = (wave >> 1) * 64;
  int frow = lane & 15, fq = lane >> 4;
  int fqs = fq ^ ((frow >> 1) & 3);         // un-swizzle on read

  for (int kt = 0; kt < 1024; kt += 32) {
#pragma unroll
    for (int it = 0; it < 2; ++it) {
      gl_lds16(aptr[it] + kt, alds[it]);
      gl_lds16(bptr[it] + kt, blds[it]);
    }
    __syncthreads();
    short8 af[4], bf[4];
#pragma unroll
    for (int i = 0; i < 4; ++i)
      af[i] = *(const short8*)(As + (wm + i * 16 + frow) * 32 + fqs * 8);
#pragma unroll
    for (int j = 0; j < 4; ++j)
      bf[j] = *(const short8*)(Bs + (wn + j * 16 + frow) * 32 + fqs * 8);
#pragma unroll
    for (int i = 0; i < 4; ++i)
#pragma unroll
      for (int j = 0; j < 4; ++j)
        acc[i][j] = __builtin_amdgcn_mfma_f32_16x16x32_bf16(af[i], bf[j], acc[i][j], 0, 0, 0);
    __syncthreads();
  }

  int col = lane & 15, qr = (lane >> 4) * 4;
#pragma unroll
  for (int j = 0; j < 4; ++j) {
    int n = wn + j * 16 + col;
    float bias = eb1[e * 4096 + h0 + hcol0 + n];
#pragma unroll
    for (int i = 0; i < 4; ++i) {
#pragma unroll
      for (int r = 0; r < 4; ++r) {
        int m = wm + i * 16 + qr + r;
        float v = fast_tanh(acc[i][j][r] + bias);
        y1[(size_t)(m0 + m) * Hc + hcol0 + n] = f2bf(v);
      }
    }
  }
}

// ------------- expert GEMM2 (batched): out[tok] += w * (y1 @ w2 [+ b2]) -----
// grid: x = d tile (fastest), y = m tile
__global__ __launch_bounds__(256) void k_gemm2(
    const u16* __restrict__ y1, const u16* __restrict__ wTc,
    const float* __restrict__ eb2, const int* __restrict__ offs,
    const int* __restrict__ perm, const float* __restrict__ aw,
    float* __restrict__ out, int h0, int Hc)
{
  int m0 = blockIdx.y * 128;
  if (m0 >= offs[8]) return;
  int e = find_expert(offs, m0);
  int n0 = blockIdx.x * 128;

  __shared__ u16 As[128 * 32];
  __shared__ u16 Bs[128 * 32];

  int tid = threadIdx.x, lane = tid & 63, wave = tid >> 6;
  int kq = lane & 3;
  int ks = kq ^ ((lane >> 3) & 3);
  const u16* wbase = wTc + (size_t)e * 1024 * Hc;
  const u16* aptr[2]; const u16* bptr[2]; u16* alds[2]; u16* blds[2];
#pragma unroll
  for (int it = 0; it < 2; ++it) {
    int chunk = wave * 2 + it;
    int r = chunk * 16 + (lane >> 2);
    aptr[it] = y1 + (size_t)(m0 + r) * Hc + ks * 8;
    bptr[it] = wbase + (size_t)(n0 + r) * Hc + ks * 8;
    alds[it] = As + chunk * 512 + lane * 8;
    blds[it] = Bs + chunk * 512 + lane * 8;
  }

  f32x4 acc[4][4] = {};
  int wm = (wave & 1) * 64, wn = (wave >> 1) * 64;
  int frow = lane & 15, fq = lane >> 4;
  int fqs = fq ^ ((frow >> 1) & 3);

  for (int kt = 0; kt < Hc; kt += 32) {
#pragma unroll
    for (int it = 0; it < 2; ++it) {
      gl_lds16(aptr[it] + kt, alds[it]);
      gl_lds16(bptr[it] + kt, blds[it]);
    }
    __syncthreads();
    short8 af[4], bf[4];
#pragma unroll
    for (int i = 0; i < 4; ++i)
      af[i] = *(const short8*)(As + (wm + i * 16 + frow) * 32 + fqs * 8);
#pragma unroll
    for (int j = 0; j < 4; ++j)
      bf[j] = *(const short8*)(Bs + (wn + j * 16 + frow) * 32 + fqs * 8);
#pragma unroll
    for (int i = 0; i < 4; ++i)
#pragma unroll
      for (int j = 0; j < 4; ++j)
        acc[i][j] = __builtin_amdgcn_mfma_f32_16x16x32_bf16(af[i], bf[j], acc[i][j], 0, 0, 0);
    __syncthreads();
  }

  int col = lane & 15, qr = (lane >> 4) * 4;
#pragma unroll
  for (int i = 0; i < 4; ++i) {
    int tokv[4]; float wv[4];
#pragma unroll
    for (int r = 0; r < 4; ++r) {
      int slot = m0 + wm + i * 16 + qr + r;
      tokv[r] = perm[slot];
      wv[r] = aw[slot];
    }
#pragma unroll
    for (int j = 0; j < 4; ++j) {
      int d = n0 + wn + j * 16 + col;
      float bias = (h0 == 0) ? eb2[e * 1024 + d] : 0.f;
#pragma unroll
      for (int r = 0; r < 4; ++r) {
        float v = acc[i][j][r] + bias;
        atomicAdd(out + (size_t)tokv[r] * 1024 + d, wv[r] * v);
      }
    }
  }
}

extern "C" void kernel_launch(void* const* d_in, const int* in_sizes, int n_in,
                              void* d_out, int out_size, void* d_ws, size_t ws_size,
                              hipStream_t stream)
{
  const float* x   = (const float*)d_in[0];
  const float* gw1 = (const float*)d_in[1];
  const float* gb1 = (const float*)d_in[2];
  const float* gw2 = (const float*)d_in[3];
  const float* gb2 = (const float*)d_in[4];
  const float* ew1 = (const float*)d_in[5];
  const float* eb1 = (const float*)d_in[6];
  const float* ew2 = (const float*)d_in[7];
  const float* eb2 = (const float*)d_in[8];
  float* out = (float*)d_out;

  char* ws = (char*)d_ws;
  int*   counts  = (int*)(ws + 0);
  int*   counts2 = (int*)(ws + 32);
  int*   offs    = (int*)(ws + 64);
  int*   tok_idx = (int*)(ws + 256);
  float* tok_w   = (float*)(ws + 131328);
  int*   perm    = (int*)(ws + 262400);
  float* aw      = (float*)(ws + 397568);
  u16*   xb      = (u16*)(ws + 1048576);           // 33.55 MB
  char*  wbase   = ws + 34603008;

  // Hc ladder: need = 34603008 + (16384 /*wTc*/ + 67584 /*y1*/) * Hc
  int Hc = 256;
  for (int c = 4096; c >= 256; c >>= 1) {
    if (34603008ull + 83968ull * c <= ws_size) { Hc = c; break; }
  }
  u16*   wTc  = (u16*)wbase;
  u16*   y1   = (u16*)(wbase + (size_t)16384 * Hc);
  float* hbuf = (float*)y1;                         // alias, dead pre-gemm

  hipMemsetAsync(d_out, 0, (size_t)B_TOK * D_MODEL * 4, stream);
  hipMemsetAsync(d_ws, 0, 64, stream);

  k_gate_h<<<dim3(128, 2), 256, 0, stream>>>(x, gw1, gb1, hbuf);
  k_gate_top2<<<4096, 256, 0, stream>>>(hbuf, gw2, gb2, tok_idx, tok_w,
                                        out + (size_t)B_TOK * D_MODEL);
  k_count<<<32, 256, 0, stream>>>(tok_idx, counts);
  k_offsets<<<1, 64, 0, stream>>>(counts, offs);
  k_perm_init<<<132, 256, 0, stream>>>(perm, aw);
  k_scatter<<<64, 256, 0, stream>>>(tok_idx, tok_w, offs, counts2, perm, aw);
  k_cast_x<<<16384, 256, 0, stream>>>(x, xb);

  for (int h0 = 0; h0 < 4096; h0 += Hc) {
    k_trans<<<dim3(Hc / 32, 32, 8), 256, 0, stream>>>(
        ew1, wTc, 4096, 0, h0, 1024, 1024 * 4096, Hc * 1024);
    k_gemm1<<<dim3(Hc / 128, SLOT_MAX / 128), 256, 0, stream>>>(
        xb, wTc, eb1, offs, perm, y1, h0, Hc);
    k_trans<<<dim3(32, Hc / 32, 8), 256, 0, stream>>>(
        ew2, wTc, 1024, h0, 0, Hc, 4096 * 1024, 1024 * Hc);
    k_gemm2<<<dim3(8, SLOT_MAX / 128), 256, 0, stream>>>(
        y1, wTc, eb2, offs, perm, aw, out, h0, Hc);
  }
}